// Round 1
// baseline (4552.288 us; speedup 1.0000x reference)
//
#include <hip/hip_runtime.h>
#include <math.h>

#define S 16384      // 128*128 spatial
#define HW 128
#define BATCH 8

__device__ __forceinline__ float mishf(float t) {
    float sp = (t > 20.0f) ? t : log1pf(expf(t));
    return t * tanhf(sp);
}

// ---------------- prep: transpose weights, combine qkv BN ----------------
__global__ void prep_kernel(const float* __restrict__ wq, const float* __restrict__ wk, const float* __restrict__ wv,
                            const float* __restrict__ bnq_s, const float* __restrict__ bnq_b,
                            const float* __restrict__ bnk_s, const float* __restrict__ bnk_b,
                            const float* __restrict__ bnv_s, const float* __restrict__ bnv_b,
                            const float* __restrict__ wpw, const float* __restrict__ wproj,
                            const float* __restrict__ wrow, const float* __restrict__ wcol,
                            float* __restrict__ wqkvT, float* __restrict__ sqkv, float* __restrict__ bqkv,
                            float* __restrict__ wpwT, float* __restrict__ wprojT,
                            float* __restrict__ wrowT, float* __restrict__ wcolT) {
    int tid = blockIdx.x * 256 + threadIdx.x;
    if (tid < 128 * 256) {            // wqkvT[ic][oc], oc: 0..63 q, 64..127 k, 128..255 v
        int ic = tid >> 8, oc = tid & 255;
        float w = (oc < 64) ? wq[oc * 128 + ic]
                : (oc < 128) ? wk[(oc - 64) * 128 + ic]
                : wv[(oc - 128) * 128 + ic];
        wqkvT[tid] = w;
    }
    if (tid < 256) {
        sqkv[tid] = (tid < 64) ? bnq_s[tid] : (tid < 128) ? bnk_s[tid - 64] : bnv_s[tid - 128];
        bqkv[tid] = (tid < 64) ? bnq_b[tid] : (tid < 128) ? bnk_b[tid - 64] : bnv_b[tid - 128];
    }
    if (tid < 256 * 128) {            // wpwT[ic(256)][oc(128)]
        int ic = tid >> 7, oc = tid & 127;
        wpwT[tid] = wpw[oc * 256 + ic];
    }
    if (tid < 128 * 128) {
        int ic = tid >> 7, oc = tid & 127;
        wprojT[tid] = wproj[oc * 128 + ic];
        wrowT[tid]  = wrow[oc * 128 + ic];
        wcolT[tid]  = wcol[oc * 128 + ic];
    }
}

// ---------------- pool (avg+max) + BN + Mish -> t0 [8,128,128,128] ----------------
__global__ void pool_kernel(const float* __restrict__ x, const float* __restrict__ s1,
                            const float* __restrict__ b1, float* __restrict__ t0) {
    int tid = blockIdx.x * 256 + threadIdx.x;   // 8*64*16384 threads
    int p = tid & (S - 1);
    int c = (tid >> 14) & 63;
    int b = tid >> 20;
    int h = p >> 7, w = p & 127;
    const float* xp = x + (size_t)(b * 64 + c) * 65536;
    float sum = 0.f, mx = -INFINITY;
    #pragma unroll
    for (int kh = -1; kh <= 1; ++kh) {
        int ih = 2 * h + kh;
        if ((unsigned)ih >= 256u) continue;
        #pragma unroll
        for (int kw = -1; kw <= 1; ++kw) {
            int iw = 2 * w + kw;
            if ((unsigned)iw >= 256u) continue;
            float v = xp[ih * 256 + iw];
            sum += v; mx = fmaxf(mx, v);
        }
    }
    float ta = (sum * (1.0f / 9.0f)) * s1[c] + b1[c];
    float tm = mx * s1[64 + c] + b1[64 + c];
    size_t o = (size_t)(b * 128 + c) * S + p;
    t0[o] = mishf(ta);
    t0[o + (size_t)64 * S] = mishf(tm);
}

// ---------------- conv3x3 (128->128, pad 1) + bias -> y ----------------
__global__ __launch_bounds__(256) void conv3x3_kernel(const float* __restrict__ t0,
                                                      const float* __restrict__ fw,
                                                      const float* __restrict__ fb,
                                                      float* __restrict__ y) {
    __shared__ float wsh[1152];            // 128 ic x 9
    __shared__ float tile[8][34][34];      // 8 ic chunk, 32x32 tile + halo
    int oc = blockIdx.y, b = blockIdx.z;
    int th0 = (blockIdx.x >> 2) * 32, tw0 = (blockIdx.x & 3) * 32;
    int tid = threadIdx.x;
    for (int i = tid; i < 1152; i += 256) wsh[i] = fw[oc * 1152 + i];
    int tx = tid & 15, ty = tid >> 4;
    int y0 = 2 * ty, x0 = 2 * tx;
    float acc00 = 0.f, acc01 = 0.f, acc10 = 0.f, acc11 = 0.f;
    for (int icc = 0; icc < 16; ++icc) {
        __syncthreads();
        for (int idx = tid; idx < 8 * 34 * 34; idx += 256) {
            int ic8 = idx / 1156;
            int r = idx - ic8 * 1156;
            int rr = r / 34;
            int cc = r - rr * 34;
            int ih = th0 + rr - 1, iw = tw0 + cc - 1;
            float v = 0.f;
            if ((unsigned)ih < 128u && (unsigned)iw < 128u)
                v = t0[(size_t)(b * 128 + icc * 8 + ic8) * S + ih * 128 + iw];
            tile[ic8][rr][cc] = v;
        }
        __syncthreads();
        #pragma unroll
        for (int ic8 = 0; ic8 < 8; ++ic8) {
            float rg[4][4];
            #pragma unroll
            for (int a = 0; a < 4; ++a)
                #pragma unroll
                for (int bb2 = 0; bb2 < 4; ++bb2)
                    rg[a][bb2] = tile[ic8][y0 + a][x0 + bb2];
            const float* wp = &wsh[(icc * 8 + ic8) * 9];
            #pragma unroll
            for (int kh = 0; kh < 3; ++kh)
                #pragma unroll
                for (int kw = 0; kw < 3; ++kw) {
                    float w = wp[kh * 3 + kw];
                    acc00 += w * rg[kh][kw];
                    acc01 += w * rg[kh][kw + 1];
                    acc10 += w * rg[kh + 1][kw];
                    acc11 += w * rg[kh + 1][kw + 1];
                }
        }
    }
    float bias = fb[oc];
    size_t base = (size_t)(b * 128 + oc) * S;
    int hh = th0 + y0, ww = tw0 + x0;
    y[base + hh * 128 + ww] = acc00 + bias;
    y[base + hh * 128 + ww + 1] = acc01 + bias;
    y[base + (hh + 1) * 128 + ww] = acc10 + bias;
    y[base + (hh + 1) * 128 + ww + 1] = acc11 + bias;
}

// ---------------- qkv 1x1: y[128] -> qkv_a[256] with BN ----------------
__global__ __launch_bounds__(256) void qkv_kernel(const float* __restrict__ y, const float* __restrict__ wT,
                                                  const float* __restrict__ sc, const float* __restrict__ bi,
                                                  float* __restrict__ qkv) {
    __shared__ float4 ylds[128][16];   // 128 ic x 64 px
    int blk = blockIdx.x;
    int b = blk >> 8;
    int p0 = (blk & 255) * 64;
    int tid = threadIdx.x;
    for (int idx = tid; idx < 128 * 16; idx += 256) {
        int ic = idx >> 4, q = idx & 15;
        ylds[ic][q] = ((const float4*)(y + (size_t)(b * 128 + ic) * S + p0))[q];
    }
    __syncthreads();
    int oc = tid;
    float4 acc[16];
    #pragma unroll
    for (int q = 0; q < 16; ++q) acc[q] = make_float4(0.f, 0.f, 0.f, 0.f);
    for (int ic = 0; ic < 128; ++ic) {
        float w = wT[ic * 256 + oc];
        #pragma unroll
        for (int q = 0; q < 16; ++q) {
            float4 v = ylds[ic][q];
            acc[q].x += w * v.x; acc[q].y += w * v.y;
            acc[q].z += w * v.z; acc[q].w += w * v.w;
        }
    }
    float s = sc[oc], bb = bi[oc];
    float4* op = (float4*)(qkv + (size_t)(b * 256 + oc) * S + p0);
    #pragma unroll
    for (int q = 0; q < 16; ++q) {
        float4 v;
        v.x = acc[q].x * s + bb; v.y = acc[q].y * s + bb;
        v.z = acc[q].z * s + bb; v.w = acc[q].w * s + bb;
        op[q] = v;
    }
}

// ---------------- per-(b,c) plane row/col means ----------------
__global__ void mean_kernel(const float* __restrict__ qkv, float* __restrict__ rowmean,
                            float* __restrict__ colmean) {
    int bc = blockIdx.x;                 // b*256+c
    const float* plane = qkv + (size_t)bc * S;
    int t = threadIdx.x;                 // 128
    float ca = 0.f;
    for (int j = 0; j < 128; ++j) ca += plane[j * 128 + t];
    colmean[bc * 128 + t] = ca * (1.f / 128.f);
    float ra = 0.f;
    for (int j = 0; j < 128; ++j) ra += plane[t * 128 + j];
    rowmean[bc * 128 + t] = ra * (1.f / 128.f);
}

// ---------------- depthwise 3x3 + BN + ReLU ----------------
__global__ void dw_kernel(const float* __restrict__ qkv, const float* __restrict__ wdw,
                          const float* __restrict__ s, const float* __restrict__ bb,
                          float* __restrict__ o) {
    int tid = blockIdx.x * 256 + threadIdx.x;  // 8*256*16384
    int p = tid & (S - 1);
    int c = (tid >> 14) & 255;
    int b = tid >> 22;
    int h = p >> 7, w = p & 127;
    const float* ip = qkv + (size_t)(b * 256 + c) * S;
    const float* wp = wdw + c * 9;
    float acc = 0.f;
    #pragma unroll
    for (int kh = 0; kh < 3; ++kh) {
        int ih = h + kh - 1;
        if ((unsigned)ih >= 128u) continue;
        #pragma unroll
        for (int kw = 0; kw < 3; ++kw) {
            int iw = w + kw - 1;
            if ((unsigned)iw >= 128u) continue;
            acc += wp[kh * 3 + kw] * ip[ih * 128 + iw];
        }
    }
    float v = acc * s[c] + bb[c];
    o[(size_t)tid] = fmaxf(v, 0.f);
}

// ---------------- pointwise 256->128 + BN ----------------
__global__ __launch_bounds__(256) void pw_kernel(const float* __restrict__ dwv, const float* __restrict__ wT,
                                                 const float* __restrict__ sc, const float* __restrict__ bi,
                                                 float* __restrict__ qb) {
    __shared__ float4 lds[256][8];    // 256 ic x 32 px
    int blk = blockIdx.x;
    int b = blk >> 9;
    int p0 = (blk & 511) * 32;
    int tid = threadIdx.x;
    for (int idx = tid; idx < 256 * 8; idx += 256) {
        int ic = idx >> 3, q = idx & 7;
        lds[ic][q] = ((const float4*)(dwv + (size_t)(b * 256 + ic) * S + p0))[q];
    }
    __syncthreads();
    int oc = tid & 127, half = tid >> 7;
    float4 acc[4];
    #pragma unroll
    for (int q = 0; q < 4; ++q) acc[q] = make_float4(0.f, 0.f, 0.f, 0.f);
    for (int ic = 0; ic < 256; ++ic) {
        float w = wT[ic * 128 + oc];
        #pragma unroll
        for (int q = 0; q < 4; ++q) {
            float4 v = lds[ic][half * 4 + q];
            acc[q].x += w * v.x; acc[q].y += w * v.y;
            acc[q].z += w * v.z; acc[q].w += w * v.w;
        }
    }
    float s = sc[oc], bb = bi[oc];
    float4* op = (float4*)(qb + (size_t)(b * 128 + oc) * S + p0 + half * 16);
    #pragma unroll
    for (int q = 0; q < 4; ++q) {
        float4 v;
        v.x = acc[q].x * s + bb; v.y = acc[q].y * s + bb;
        v.z = acc[q].z * s + bb; v.w = acc[q].w * s + bb;
        op[q] = v;
    }
}

// ---------------- axial attention (row or col) -> relu'd output ----------------
__global__ __launch_bounds__(128) void attn_kernel(const float* __restrict__ meanbuf,  // [8][256][128]
                                                   const float* __restrict__ posq,
                                                   const float* __restrict__ posk,
                                                   float* __restrict__ xact) {        // [8][128][128]
    __shared__ float qr[8][128], kr[8][128], vr[16][128];
    int b = blockIdx.x >> 3, head = blockIdx.x & 7;
    int i = threadIdx.x;
    // half-pixel linear resize 16 -> 128, edge-clamped
    float src = (i + 0.5f) * 0.125f - 0.5f;
    src = fmaxf(src, 0.f);
    int i0 = (int)src;
    if (i0 > 15) i0 = 15;
    float f = src - (float)i0;
    int i1 = (i0 + 1 > 15) ? 15 : i0 + 1;
    const float* mb = meanbuf + (size_t)b * 256 * 128;
    for (int kd = 0; kd < 8; ++kd) {
        int cq = head * 8 + kd;
        qr[kd][i] = mb[cq * 128 + i] + posq[cq * 16 + i0] * (1.f - f) + posq[cq * 16 + i1] * f;
        kr[kd][i] = mb[(64 + cq) * 128 + i] + posk[cq * 16 + i0] * (1.f - f) + posk[cq * 16 + i1] * f;
    }
    for (int d = 0; d < 16; ++d)
        vr[d][i] = mb[(128 + head * 16 + d) * 128 + i];
    __syncthreads();
    float qreg[8];
    #pragma unroll
    for (int kd = 0; kd < 8; ++kd) qreg[kd] = qr[kd][i];
    const float scale = 0.35355339059327373f;   // 8^-0.5
    float m = -INFINITY;
    for (int j = 0; j < 128; ++j) {
        float sj = 0.f;
        #pragma unroll
        for (int kd = 0; kd < 8; ++kd) sj += qreg[kd] * kr[kd][j];
        m = fmaxf(m, sj * scale);
    }
    float denom = 0.f;
    float acc[16];
    #pragma unroll
    for (int d = 0; d < 16; ++d) acc[d] = 0.f;
    for (int j = 0; j < 128; ++j) {
        float sj = 0.f;
        #pragma unroll
        for (int kd = 0; kd < 8; ++kd) sj += qreg[kd] * kr[kd][j];
        float pj = expf(sj * scale - m);
        denom += pj;
        #pragma unroll
        for (int d = 0; d < 16; ++d) acc[d] += pj * vr[d][j];
    }
    float inv = 1.f / denom;
    float* xp = xact + ((size_t)b * 128 + head * 16) * 128;
    for (int d = 0; d < 16; ++d)
        xp[d * 128 + i] = fmaxf(acc[d] * inv, 0.f);   // relu before 1x1 conv
}

// ---------------- 1x1 conv on xr/xc (128->128) + BN ----------------
__global__ __launch_bounds__(256) void rc_conv_kernel(const float* __restrict__ xr_act, const float* __restrict__ xc_act,
                                                      const float* __restrict__ wrowT, const float* __restrict__ wcolT,
                                                      const float* __restrict__ rs, const float* __restrict__ rb,
                                                      const float* __restrict__ cs, const float* __restrict__ cb,
                                                      float* __restrict__ xr_conv, float* __restrict__ xc_conv) {
    __shared__ float4 lds[128][16];   // 128 ic x 64 positions
    int blk = blockIdx.x;             // 0..31
    int iscol = blk >> 4;
    int rem = blk & 15;
    int b = rem >> 1;
    int i0 = (rem & 1) * 64;
    const float* src = iscol ? xc_act : xr_act;
    const float* wT  = iscol ? wcolT : wrowT;
    const float* ss  = iscol ? cs : rs;
    const float* sb  = iscol ? cb : rb;
    float* dst       = iscol ? xc_conv : xr_conv;
    int tid = threadIdx.x;
    const float4* src4 = (const float4*)(src + (size_t)b * 16384 + i0);
    for (int idx = tid; idx < 128 * 16; idx += 256) {
        int ic = idx >> 4, q = idx & 15;
        lds[ic][q] = src4[ic * 32 + q];
    }
    __syncthreads();
    int oc = tid & 127, sub = tid >> 7;
    float4 acc[8];
    #pragma unroll
    for (int q = 0; q < 8; ++q) acc[q] = make_float4(0.f, 0.f, 0.f, 0.f);
    for (int ic = 0; ic < 128; ++ic) {
        float w = wT[ic * 128 + oc];
        #pragma unroll
        for (int q = 0; q < 8; ++q) {
            float4 v = lds[ic][sub * 8 + q];
            acc[q].x += w * v.x; acc[q].y += w * v.y;
            acc[q].z += w * v.z; acc[q].w += w * v.w;
        }
    }
    float s = ss[oc], bb = sb[oc];
    float4* op = (float4*)(dst + (size_t)(b * 128 + oc) * 128 + i0 + sub * 32);
    #pragma unroll
    for (int q = 0; q < 8; ++q) {
        float4 v;
        v.x = acc[q].x * s + bb; v.y = acc[q].y * s + bb;
        v.z = acc[q].z * s + bb; v.w = acc[q].w * s + bb;
        op[q] = v;
    }
}

// ---------------- final: xx = v+xr+xc, relu, 1x1 proj+BN, hsigmoid * qkv_b ----------------
__global__ __launch_bounds__(256) void final_kernel(const float* __restrict__ qkv_a,
                                                    const float* __restrict__ xr_conv, const float* __restrict__ xc_conv,
                                                    const float* __restrict__ wprojT,
                                                    const float* __restrict__ ps, const float* __restrict__ pb,
                                                    const float* __restrict__ qkv_b, float* __restrict__ out) {
    __shared__ float alds[128][32];   // relu(xx), 128 ic x 32 px
    int blk = blockIdx.x;
    int b = blk >> 9;
    int p0 = (blk & 511) * 32;
    int h = p0 >> 7, w0 = p0 & 127;
    int tid = threadIdx.x;
    const float* vbase = qkv_a + ((size_t)b * 256 + 128) * S;
    for (int idx = tid; idx < 128 * 32; idx += 256) {
        int ic = idx >> 5, px = idx & 31;
        float xx = vbase[(size_t)ic * S + p0 + px]
                 + xr_conv[(b * 128 + ic) * 128 + h]
                 + xc_conv[(b * 128 + ic) * 128 + w0 + px];
        alds[ic][px] = fmaxf(xx, 0.f);
    }
    __syncthreads();
    int oc = tid & 127, half = tid >> 7;
    float4 acc[4];
    #pragma unroll
    for (int q = 0; q < 4; ++q) acc[q] = make_float4(0.f, 0.f, 0.f, 0.f);
    for (int ic = 0; ic < 128; ++ic) {
        float w = wprojT[ic * 128 + oc];
        const float4* row = (const float4*)&alds[ic][half * 16];
        #pragma unroll
        for (int q = 0; q < 4; ++q) {
            float4 v = row[q];
            acc[q].x += w * v.x; acc[q].y += w * v.y;
            acc[q].z += w * v.z; acc[q].w += w * v.w;
        }
    }
    float s = ps[oc], bb = pb[oc];
    const float4* qb = (const float4*)(qkv_b + (size_t)(b * 128 + oc) * S + p0 + half * 16);
    float4* op = (float4*)(out + (size_t)(b * 128 + oc) * S + p0 + half * 16);
    #pragma unroll
    for (int q = 0; q < 4; ++q) {
        float4 g = qb[q];
        float4 v;
        float t;
        t = acc[q].x * s + bb; v.x = fminf(fmaxf(t + 3.f, 0.f), 6.f) * (1.f / 6.f) * g.x;
        t = acc[q].y * s + bb; v.y = fminf(fmaxf(t + 3.f, 0.f), 6.f) * (1.f / 6.f) * g.y;
        t = acc[q].z * s + bb; v.z = fminf(fmaxf(t + 3.f, 0.f), 6.f) * (1.f / 6.f) * g.z;
        t = acc[q].w * s + bb; v.w = fminf(fmaxf(t + 3.f, 0.f), 6.f) * (1.f / 6.f) * g.w;
        op[q] = v;
    }
}

extern "C" void kernel_launch(void* const* d_in, const int* in_sizes, int n_in,
                              void* d_out, int out_size, void* d_ws, size_t ws_size,
                              hipStream_t stream) {
    const float* x       = (const float*)d_in[0];
    const float* bn1_s   = (const float*)d_in[1];
    const float* bn1_b   = (const float*)d_in[2];
    const float* fc1_w   = (const float*)d_in[3];
    const float* fc1_b   = (const float*)d_in[4];
    const float* wq      = (const float*)d_in[5];
    const float* bnq_s   = (const float*)d_in[6];
    const float* bnq_b   = (const float*)d_in[7];
    const float* wk      = (const float*)d_in[8];
    const float* bnk_s   = (const float*)d_in[9];
    const float* bnk_b   = (const float*)d_in[10];
    const float* wv      = (const float*)d_in[11];
    const float* bnv_s   = (const float*)d_in[12];
    const float* bnv_b   = (const float*)d_in[13];
    const float* pos_rq  = (const float*)d_in[14];
    const float* pos_rk  = (const float*)d_in[15];
    const float* pos_cq  = (const float*)d_in[16];
    const float* pos_ck  = (const float*)d_in[17];
    const float* wrow    = (const float*)d_in[18];
    const float* bnrow_s = (const float*)d_in[19];
    const float* bnrow_b = (const float*)d_in[20];
    const float* wcol    = (const float*)d_in[21];
    const float* bncol_s = (const float*)d_in[22];
    const float* bncol_b = (const float*)d_in[23];
    const float* wproj   = (const float*)d_in[24];
    const float* bnproj_s= (const float*)d_in[25];
    const float* bnproj_b= (const float*)d_in[26];
    const float* wdw     = (const float*)d_in[27];
    const float* bndw_s  = (const float*)d_in[28];
    const float* bndw_b  = (const float*)d_in[29];
    const float* wpw     = (const float*)d_in[30];
    const float* bnpw_s  = (const float*)d_in[31];
    const float* bnpw_b  = (const float*)d_in[32];

    char* ws = (char*)d_ws;
    float* qkv_a  = (float*)(ws);                                       // 134217728 B [8,256,128,128]
    float* t0     = (float*)(ws + (size_t)134217728);                   // 67108864 B
    float* ybuf   = (float*)(ws + (size_t)134217728 + 67108864);        // 67108864 B
    float* qkv_dw = t0;                                                 // reuse region B after qkv done
    float* qkv_b  = (float*)(ws + (size_t)268435456);                   // 67108864 B
    char* sm = ws + (size_t)335544320;
    float* rowmean = (float*)sm; sm += 1048576;
    float* colmean = (float*)sm; sm += 1048576;
    float* xr_act  = (float*)sm; sm += 524288;
    float* xc_act  = (float*)sm; sm += 524288;
    float* xr_conv = (float*)sm; sm += 524288;
    float* xc_conv = (float*)sm; sm += 524288;
    float* wqkvT   = (float*)sm; sm += 131072;
    float* sqkv    = (float*)sm; sm += 1024;
    float* bqkv    = (float*)sm; sm += 1024;
    float* wpwT    = (float*)sm; sm += 131072;
    float* wprojT  = (float*)sm; sm += 65536;
    float* wrowT   = (float*)sm; sm += 65536;
    float* wcolT   = (float*)sm; sm += 65536;

    float* out = (float*)d_out;

    prep_kernel<<<128, 256, 0, stream>>>(wq, wk, wv, bnq_s, bnq_b, bnk_s, bnk_b, bnv_s, bnv_b,
                                         wpw, wproj, wrow, wcol,
                                         wqkvT, sqkv, bqkv, wpwT, wprojT, wrowT, wcolT);
    pool_kernel<<<32768, 256, 0, stream>>>(x, bn1_s, bn1_b, t0);
    conv3x3_kernel<<<dim3(16, 128, 8), 256, 0, stream>>>(t0, fc1_w, fc1_b, ybuf);
    qkv_kernel<<<2048, 256, 0, stream>>>(ybuf, wqkvT, sqkv, bqkv, qkv_a);
    mean_kernel<<<2048, 128, 0, stream>>>(qkv_a, rowmean, colmean);
    dw_kernel<<<131072, 256, 0, stream>>>(qkv_a, wdw, bndw_s, bndw_b, qkv_dw);
    pw_kernel<<<4096, 256, 0, stream>>>(qkv_dw, wpwT, bnpw_s, bnpw_b, qkv_b);
    attn_kernel<<<64, 128, 0, stream>>>(rowmean, pos_rq, pos_rk, xr_act);
    attn_kernel<<<64, 128, 0, stream>>>(colmean, pos_cq, pos_ck, xc_act);
    rc_conv_kernel<<<32, 256, 0, stream>>>(xr_act, xc_act, wrowT, wcolT,
                                           bnrow_s, bnrow_b, bncol_s, bncol_b, xr_conv, xc_conv);
    final_kernel<<<4096, 256, 0, stream>>>(qkv_a, xr_conv, xc_conv, wprojT,
                                           bnproj_s, bnproj_b, qkv_b, out);
}

// Round 2
// 1130.187 us; speedup vs baseline: 4.0279x; 4.0279x over previous
//
#include <hip/hip_runtime.h>
#include <math.h>

#define S 16384      // 128*128 spatial
#define HW 128
#define BATCH 8

typedef __attribute__((ext_vector_type(8))) short short8;
typedef __attribute__((ext_vector_type(4))) float f32x4;

__device__ __forceinline__ float mishf(float t) {
    float sp = (t > 20.0f) ? t : log1pf(expf(t));
    return t * tanhf(sp);
}
__device__ __forceinline__ short f2bf(float f) {   // RNE f32 -> bf16 bits
    unsigned u = __float_as_uint(f);
    unsigned r = (u + 0x7FFFu + ((u >> 16) & 1u)) >> 16;
    return (short)r;
}
__device__ __forceinline__ float bf2f(short s) {
    unsigned u = ((unsigned)(unsigned short)s) << 16;
    return __uint_as_float(u);
}
__device__ __forceinline__ unsigned packhl(float v) {  // lo16=hi part, hi16=lo part
    short h = f2bf(v);
    short l = f2bf(v - bf2f(h));
    return (unsigned)(unsigned short)h | ((unsigned)(unsigned short)l << 16);
}

// ---------------- prep: transpose weights, combine qkv BN, split conv weights ----------------
__global__ void prep_kernel(const float* __restrict__ wq, const float* __restrict__ wk, const float* __restrict__ wv,
                            const float* __restrict__ bnq_s, const float* __restrict__ bnq_b,
                            const float* __restrict__ bnk_s, const float* __restrict__ bnk_b,
                            const float* __restrict__ bnv_s, const float* __restrict__ bnv_b,
                            const float* __restrict__ wpw, const float* __restrict__ wproj,
                            const float* __restrict__ wrow, const float* __restrict__ wcol,
                            const float* __restrict__ fc1_w,
                            float* __restrict__ wqkvT, float* __restrict__ sqkv, float* __restrict__ bqkv,
                            float* __restrict__ wpwT, float* __restrict__ wprojT,
                            float* __restrict__ wrowT, float* __restrict__ wcolT,
                            short* __restrict__ wch, short* __restrict__ wcl) {
    int tid = blockIdx.x * 256 + threadIdx.x;
    if (tid < 128 * 256) {            // wqkvT[ic][oc], oc: 0..63 q, 64..127 k, 128..255 v
        int ic = tid >> 8, oc = tid & 255;
        float w = (oc < 64) ? wq[oc * 128 + ic]
                : (oc < 128) ? wk[(oc - 64) * 128 + ic]
                : wv[(oc - 128) * 128 + ic];
        wqkvT[tid] = w;
    }
    if (tid < 256) {
        sqkv[tid] = (tid < 64) ? bnq_s[tid] : (tid < 128) ? bnk_s[tid - 64] : bnv_s[tid - 128];
        bqkv[tid] = (tid < 64) ? bnq_b[tid] : (tid < 128) ? bnk_b[tid - 64] : bnv_b[tid - 128];
    }
    if (tid < 256 * 128) {            // wpwT[ic(256)][oc(128)]
        int ic = tid >> 7, oc = tid & 127;
        wpwT[tid] = wpw[oc * 256 + ic];
    }
    if (tid < 128 * 128) {
        int ic = tid >> 7, oc = tid & 127;
        wprojT[tid] = wproj[oc * 128 + ic];
        wrowT[tid]  = wrow[oc * 128 + ic];
        wcolT[tid]  = wcol[oc * 128 + ic];
    }
    if (tid < 9 * 128 * 128) {        // wch/wcl [tap][oc][ic] bf16 hi/lo split
        int tap = tid >> 14;
        int oc = (tid >> 7) & 127;
        int ic = tid & 127;
        float f = fc1_w[(oc * 128 + ic) * 9 + tap];
        short h = f2bf(f);
        wch[tid] = h;
        wcl[tid] = f2bf(f - bf2f(h));
    }
}

// ---------------- pool (avg+max) + BN + Mish -> padded NHWC bf16 hi/lo ----------------
// t0p layout: [8][130][130][128] bf16 (borders pre-zeroed by memset)
__global__ __launch_bounds__(256) void pool_kernel(const float* __restrict__ x,
                                                   const float* __restrict__ s1, const float* __restrict__ b1,
                                                   short* __restrict__ t0ph, short* __restrict__ t0pl) {
    __shared__ unsigned ot[64][132];   // [w-local][c] packed hi|lo
    int bx = blockIdx.x;               // 0..255
    int b = blockIdx.y;
    int h = bx >> 1, wh = bx & 1;
    int t = threadIdx.x;
    int wl = t & 63, c2 = t >> 6;      // c2 in 0..3
    int w = wh * 64 + wl;
    for (int cs = 0; cs < 16; ++cs) {
        int c = cs * 4 + c2;           // 0..63
        const float* xp = x + (size_t)(b * 64 + c) * 65536;
        float sum = 0.f, mx = -INFINITY;
        #pragma unroll
        for (int kh = 0; kh < 3; ++kh) {
            int ih = 2 * h + kh - 1;
            if ((unsigned)ih >= 256u) continue;
            #pragma unroll
            for (int kw = 0; kw < 3; ++kw) {
                int iw = 2 * w + kw - 1;
                if ((unsigned)iw >= 256u) continue;
                float v = xp[ih * 256 + iw];
                sum += v; mx = fmaxf(mx, v);
            }
        }
        float ta = mishf((sum * (1.f / 9.f)) * s1[c] + b1[c]);
        float tm = mishf(mx * s1[64 + c] + b1[64 + c]);
        ot[wl][c] = packhl(ta);
        ot[wl][64 + c] = packhl(tm);
    }
    __syncthreads();
    size_t rowbase = ((size_t)(b * 130 + h + 1) * 130 + 1 + wh * 64) * 128;
    short* oph = t0ph + rowbase;
    short* opl = t0pl + rowbase;
    for (int idx = t; idx < 64 * 16; idx += 256) {
        int wloc = idx >> 4, co = idx & 15;
        short8 hv, lv;
        #pragma unroll
        for (int j = 0; j < 8; ++j) {
            unsigned u = ot[wloc][co * 8 + j];
            hv[j] = (short)(u & 0xFFFFu);
            lv[j] = (short)(u >> 16);
        }
        *(short8*)(oph + wloc * 128 + co * 8) = hv;
        *(short8*)(opl + wloc * 128 + co * 8) = lv;
    }
}

// ---------------- conv3x3 (128->128, pad 1) via MFMA bf16x3 -> y f32 NCHW ----------------
__global__ __launch_bounds__(256) void conv3x3_mfma(const short* __restrict__ t0ph,
                                                    const short* __restrict__ t0pl,
                                                    const short* __restrict__ wch, const short* __restrict__ wcl,
                                                    const float* __restrict__ fb, float* __restrict__ y) {
    int h = blockIdx.x, b = blockIdx.y;
    int tid = threadIdx.x, lane = tid & 63, wid = tid >> 6;
    int wr = wid >> 1, wc2 = wid & 1;      // spatial half / oc half
    int l15 = lane & 15, l4 = lane >> 4;
    f32x4 acc[4][4];
    #pragma unroll
    for (int m = 0; m < 4; ++m)
        #pragma unroll
        for (int n = 0; n < 4; ++n) acc[m][n] = (f32x4){0.f, 0.f, 0.f, 0.f};
    int spb = wr * 64 + l15;
    int ocb = wc2 * 64 + l15;
    for (int kh = 0; kh < 3; ++kh) {
        const size_t rowoff = ((size_t)(b * 130 + h + kh) * 130) * 128;
        for (int kw = 0; kw < 3; ++kw) {
            const short* ah = t0ph + rowoff + (size_t)kw * 128;
            const short* al = t0pl + rowoff + (size_t)kw * 128;
            const short* wh = wch + (size_t)(kh * 3 + kw) * 16384;
            const short* wl = wcl + (size_t)(kh * 3 + kw) * 16384;
            #pragma unroll
            for (int ks = 0; ks < 4; ++ks) {
                int k0 = ks * 32 + l4 * 8;
                short8 a_h[4], b_h[4];
                #pragma unroll
                for (int m = 0; m < 4; ++m) a_h[m] = *(const short8*)(ah + (spb + m * 16) * 128 + k0);
                #pragma unroll
                for (int n = 0; n < 4; ++n) b_h[n] = *(const short8*)(wh + (ocb + n * 16) * 128 + k0);
                #pragma unroll
                for (int m = 0; m < 4; ++m)
                    #pragma unroll
                    for (int n = 0; n < 4; ++n)
                        acc[m][n] = __builtin_amdgcn_mfma_f32_16x16x32_bf16(a_h[m], b_h[n], acc[m][n], 0, 0, 0);
                short8 a_l[4];
                #pragma unroll
                for (int m = 0; m < 4; ++m) a_l[m] = *(const short8*)(al + (spb + m * 16) * 128 + k0);
                #pragma unroll
                for (int m = 0; m < 4; ++m)
                    #pragma unroll
                    for (int n = 0; n < 4; ++n)
                        acc[m][n] = __builtin_amdgcn_mfma_f32_16x16x32_bf16(a_l[m], b_h[n], acc[m][n], 0, 0, 0);
                short8 b_l[4];
                #pragma unroll
                for (int n = 0; n < 4; ++n) b_l[n] = *(const short8*)(wl + (ocb + n * 16) * 128 + k0);
                #pragma unroll
                for (int m = 0; m < 4; ++m)
                    #pragma unroll
                    for (int n = 0; n < 4; ++n)
                        acc[m][n] = __builtin_amdgcn_mfma_f32_16x16x32_bf16(a_h[m], b_l[n], acc[m][n], 0, 0, 0);
            }
        }
    }
    // epilogue: transpose to NCHW via LDS (two oc-half passes), add bias
    __shared__ float tr[64][129];
    int hbase = h * 128;
    #pragma unroll 1
    for (int p = 0; p < 2; ++p) {
        __syncthreads();
        if (wc2 == p) {
            #pragma unroll
            for (int n = 0; n < 4; ++n)
                #pragma unroll
                for (int m = 0; m < 4; ++m)
                    #pragma unroll
                    for (int r = 0; r < 4; ++r)
                        tr[n * 16 + l15][wr * 64 + m * 16 + l4 * 4 + r] = acc[m][n][r];
        }
        __syncthreads();
        int ocl = tid >> 2, q = tid & 3;
        int oc = p * 64 + ocl;
        float bias = fb[oc];
        float* yp = y + (size_t)(b * 128 + oc) * S + hbase + q * 32;
        #pragma unroll
        for (int j = 0; j < 32; j += 4) {
            float4 v;
            v.x = tr[ocl][q * 32 + j]     + bias;
            v.y = tr[ocl][q * 32 + j + 1] + bias;
            v.z = tr[ocl][q * 32 + j + 2] + bias;
            v.w = tr[ocl][q * 32 + j + 3] + bias;
            *(float4*)(yp + j) = v;
        }
    }
}

// ---------------- qkv 1x1: y[128] -> qkv_a[256] with BN ----------------
__global__ __launch_bounds__(256) void qkv_kernel(const float* __restrict__ y, const float* __restrict__ wT,
                                                  const float* __restrict__ sc, const float* __restrict__ bi,
                                                  float* __restrict__ qkv) {
    __shared__ float4 ylds[128][16];   // 128 ic x 64 px
    int blk = blockIdx.x;
    int b = blk >> 8;
    int p0 = (blk & 255) * 64;
    int tid = threadIdx.x;
    for (int idx = tid; idx < 128 * 16; idx += 256) {
        int ic = idx >> 4, q = idx & 15;
        ylds[ic][q] = ((const float4*)(y + (size_t)(b * 128 + ic) * S + p0))[q];
    }
    __syncthreads();
    int oc = tid;
    float4 acc[16];
    #pragma unroll
    for (int q = 0; q < 16; ++q) acc[q] = make_float4(0.f, 0.f, 0.f, 0.f);
    for (int ic = 0; ic < 128; ++ic) {
        float w = wT[ic * 256 + oc];
        #pragma unroll
        for (int q = 0; q < 16; ++q) {
            float4 v = ylds[ic][q];
            acc[q].x += w * v.x; acc[q].y += w * v.y;
            acc[q].z += w * v.z; acc[q].w += w * v.w;
        }
    }
    float s = sc[oc], bb = bi[oc];
    float4* op = (float4*)(qkv + (size_t)(b * 256 + oc) * S + p0);
    #pragma unroll
    for (int q = 0; q < 16; ++q) {
        float4 v;
        v.x = acc[q].x * s + bb; v.y = acc[q].y * s + bb;
        v.z = acc[q].z * s + bb; v.w = acc[q].w * s + bb;
        op[q] = v;
    }
}

// ---------------- per-(b,c) plane row/col means ----------------
__global__ void mean_kernel(const float* __restrict__ qkv, float* __restrict__ rowmean,
                            float* __restrict__ colmean) {
    int bc = blockIdx.x;                 // b*256+c
    const float* plane = qkv + (size_t)bc * S;
    int t = threadIdx.x;                 // 128
    float ca = 0.f;
    for (int j = 0; j < 128; ++j) ca += plane[j * 128 + t];
    colmean[bc * 128 + t] = ca * (1.f / 128.f);
    float ra = 0.f;
    for (int j = 0; j < 128; ++j) ra += plane[t * 128 + j];
    rowmean[bc * 128 + t] = ra * (1.f / 128.f);
}

// ---------------- depthwise 3x3 + BN + ReLU ----------------
__global__ void dw_kernel(const float* __restrict__ qkv, const float* __restrict__ wdw,
                          const float* __restrict__ s, const float* __restrict__ bb,
                          float* __restrict__ o) {
    int tid = blockIdx.x * 256 + threadIdx.x;  // 8*256*16384
    int p = tid & (S - 1);
    int c = (tid >> 14) & 255;
    int b = tid >> 22;
    int h = p >> 7, w = p & 127;
    const float* ip = qkv + (size_t)(b * 256 + c) * S;
    const float* wp = wdw + c * 9;
    float acc = 0.f;
    #pragma unroll
    for (int kh = 0; kh < 3; ++kh) {
        int ih = h + kh - 1;
        if ((unsigned)ih >= 128u) continue;
        #pragma unroll
        for (int kw = 0; kw < 3; ++kw) {
            int iw = w + kw - 1;
            if ((unsigned)iw >= 128u) continue;
            acc += wp[kh * 3 + kw] * ip[ih * 128 + iw];
        }
    }
    float v = acc * s[c] + bb[c];
    o[(size_t)tid] = fmaxf(v, 0.f);
}

// ---------------- pointwise 256->128 + BN ----------------
__global__ __launch_bounds__(256) void pw_kernel(const float* __restrict__ dwv, const float* __restrict__ wT,
                                                 const float* __restrict__ sc, const float* __restrict__ bi,
                                                 float* __restrict__ qb) {
    __shared__ float4 lds[256][8];    // 256 ic x 32 px
    int blk = blockIdx.x;
    int b = blk >> 9;
    int p0 = (blk & 511) * 32;
    int tid = threadIdx.x;
    for (int idx = tid; idx < 256 * 8; idx += 256) {
        int ic = idx >> 3, q = idx & 7;
        lds[ic][q] = ((const float4*)(dwv + (size_t)(b * 256 + ic) * S + p0))[q];
    }
    __syncthreads();
    int oc = tid & 127, half = tid >> 7;
    float4 acc[4];
    #pragma unroll
    for (int q = 0; q < 4; ++q) acc[q] = make_float4(0.f, 0.f, 0.f, 0.f);
    for (int ic = 0; ic < 256; ++ic) {
        float w = wT[ic * 128 + oc];
        #pragma unroll
        for (int q = 0; q < 4; ++q) {
            float4 v = lds[ic][half * 4 + q];
            acc[q].x += w * v.x; acc[q].y += w * v.y;
            acc[q].z += w * v.z; acc[q].w += w * v.w;
        }
    }
    float s = sc[oc], bb = bi[oc];
    float4* op = (float4*)(qb + (size_t)(b * 128 + oc) * S + p0 + half * 16);
    #pragma unroll
    for (int q = 0; q < 4; ++q) {
        float4 v;
        v.x = acc[q].x * s + bb; v.y = acc[q].y * s + bb;
        v.z = acc[q].z * s + bb; v.w = acc[q].w * s + bb;
        op[q] = v;
    }
}

// ---------------- axial attention (row or col) -> relu'd output ----------------
__global__ __launch_bounds__(128) void attn_kernel(const float* __restrict__ meanbuf,  // [8][256][128]
                                                   const float* __restrict__ posq,
                                                   const float* __restrict__ posk,
                                                   float* __restrict__ xact) {        // [8][128][128]
    __shared__ float qr[8][128], kr[8][128], vr[16][128];
    int b = blockIdx.x >> 3, head = blockIdx.x & 7;
    int i = threadIdx.x;
    float src = (i + 0.5f) * 0.125f - 0.5f;
    src = fmaxf(src, 0.f);
    int i0 = (int)src;
    if (i0 > 15) i0 = 15;
    float f = src - (float)i0;
    int i1 = (i0 + 1 > 15) ? 15 : i0 + 1;
    const float* mb = meanbuf + (size_t)b * 256 * 128;
    for (int kd = 0; kd < 8; ++kd) {
        int cq = head * 8 + kd;
        qr[kd][i] = mb[cq * 128 + i] + posq[cq * 16 + i0] * (1.f - f) + posq[cq * 16 + i1] * f;
        kr[kd][i] = mb[(64 + cq) * 128 + i] + posk[cq * 16 + i0] * (1.f - f) + posk[cq * 16 + i1] * f;
    }
    for (int d = 0; d < 16; ++d)
        vr[d][i] = mb[(128 + head * 16 + d) * 128 + i];
    __syncthreads();
    float qreg[8];
    #pragma unroll
    for (int kd = 0; kd < 8; ++kd) qreg[kd] = qr[kd][i];
    const float scale = 0.35355339059327373f;   // 8^-0.5
    float m = -INFINITY;
    for (int j = 0; j < 128; ++j) {
        float sj = 0.f;
        #pragma unroll
        for (int kd = 0; kd < 8; ++kd) sj += qreg[kd] * kr[kd][j];
        m = fmaxf(m, sj * scale);
    }
    float denom = 0.f;
    float acc[16];
    #pragma unroll
    for (int d = 0; d < 16; ++d) acc[d] = 0.f;
    for (int j = 0; j < 128; ++j) {
        float sj = 0.f;
        #pragma unroll
        for (int kd = 0; kd < 8; ++kd) sj += qreg[kd] * kr[kd][j];
        float pj = expf(sj * scale - m);
        denom += pj;
        #pragma unroll
        for (int d = 0; d < 16; ++d) acc[d] += pj * vr[d][j];
    }
    float inv = 1.f / denom;
    float* xp = xact + ((size_t)b * 128 + head * 16) * 128;
    for (int d = 0; d < 16; ++d)
        xp[d * 128 + i] = fmaxf(acc[d] * inv, 0.f);   // relu before 1x1 conv
}

// ---------------- 1x1 conv on xr/xc (128->128) + BN ----------------
__global__ __launch_bounds__(256) void rc_conv_kernel(const float* __restrict__ xr_act, const float* __restrict__ xc_act,
                                                      const float* __restrict__ wrowT, const float* __restrict__ wcolT,
                                                      const float* __restrict__ rs, const float* __restrict__ rb,
                                                      const float* __restrict__ cs, const float* __restrict__ cb,
                                                      float* __restrict__ xr_conv, float* __restrict__ xc_conv) {
    __shared__ float4 lds[128][16];   // 128 ic x 64 positions
    int blk = blockIdx.x;             // 0..31
    int iscol = blk >> 4;
    int rem = blk & 15;
    int b = rem >> 1;
    int i0 = (rem & 1) * 64;
    const float* src = iscol ? xc_act : xr_act;
    const float* wT  = iscol ? wcolT : wrowT;
    const float* ss  = iscol ? cs : rs;
    const float* sb  = iscol ? cb : rb;
    float* dst       = iscol ? xc_conv : xr_conv;
    int tid = threadIdx.x;
    const float4* src4 = (const float4*)(src + (size_t)b * 16384 + i0);
    for (int idx = tid; idx < 128 * 16; idx += 256) {
        int ic = idx >> 4, q = idx & 15;
        lds[ic][q] = src4[ic * 32 + q];
    }
    __syncthreads();
    int oc = tid & 127, sub = tid >> 7;
    float4 acc[8];
    #pragma unroll
    for (int q = 0; q < 8; ++q) acc[q] = make_float4(0.f, 0.f, 0.f, 0.f);
    for (int ic = 0; ic < 128; ++ic) {
        float w = wT[ic * 128 + oc];
        #pragma unroll
        for (int q = 0; q < 8; ++q) {
            float4 v = lds[ic][sub * 8 + q];
            acc[q].x += w * v.x; acc[q].y += w * v.y;
            acc[q].z += w * v.z; acc[q].w += w * v.w;
        }
    }
    float s = ss[oc], bb = sb[oc];
    float4* op = (float4*)(dst + (size_t)(b * 128 + oc) * 128 + i0 + sub * 32);
    #pragma unroll
    for (int q = 0; q < 8; ++q) {
        float4 v;
        v.x = acc[q].x * s + bb; v.y = acc[q].y * s + bb;
        v.z = acc[q].z * s + bb; v.w = acc[q].w * s + bb;
        op[q] = v;
    }
}

// ---------------- final: xx = v+xr+xc, relu, 1x1 proj+BN, hsigmoid * qkv_b ----------------
__global__ __launch_bounds__(256) void final_kernel(const float* __restrict__ qkv_a,
                                                    const float* __restrict__ xr_conv, const float* __restrict__ xc_conv,
                                                    const float* __restrict__ wprojT,
                                                    const float* __restrict__ ps, const float* __restrict__ pb,
                                                    const float* __restrict__ qkv_b, float* __restrict__ out) {
    __shared__ float alds[128][32];   // relu(xx), 128 ic x 32 px
    int blk = blockIdx.x;
    int b = blk >> 9;
    int p0 = (blk & 511) * 32;
    int h = p0 >> 7, w0 = p0 & 127;
    int tid = threadIdx.x;
    const float* vbase = qkv_a + ((size_t)b * 256 + 128) * S;
    for (int idx = tid; idx < 128 * 32; idx += 256) {
        int ic = idx >> 5, px = idx & 31;
        float xx = vbase[(size_t)ic * S + p0 + px]
                 + xr_conv[(b * 128 + ic) * 128 + h]
                 + xc_conv[(b * 128 + ic) * 128 + w0 + px];
        alds[ic][px] = fmaxf(xx, 0.f);
    }
    __syncthreads();
    int oc = tid & 127, half = tid >> 7;
    float4 acc[4];
    #pragma unroll
    for (int q = 0; q < 4; ++q) acc[q] = make_float4(0.f, 0.f, 0.f, 0.f);
    for (int ic = 0; ic < 128; ++ic) {
        float w = wprojT[ic * 128 + oc];
        const float4* row = (const float4*)&alds[ic][half * 16];
        #pragma unroll
        for (int q = 0; q < 4; ++q) {
            float4 v = row[q];
            acc[q].x += w * v.x; acc[q].y += w * v.y;
            acc[q].z += w * v.z; acc[q].w += w * v.w;
        }
    }
    float s = ps[oc], bb = pb[oc];
    const float4* qb = (const float4*)(qkv_b + (size_t)(b * 128 + oc) * S + p0 + half * 16);
    float4* op = (float4*)(out + (size_t)(b * 128 + oc) * S + p0 + half * 16);
    #pragma unroll
    for (int q = 0; q < 4; ++q) {
        float4 g = qb[q];
        float4 v;
        float t;
        t = acc[q].x * s + bb; v.x = fminf(fmaxf(t + 3.f, 0.f), 6.f) * (1.f / 6.f) * g.x;
        t = acc[q].y * s + bb; v.y = fminf(fmaxf(t + 3.f, 0.f), 6.f) * (1.f / 6.f) * g.y;
        t = acc[q].z * s + bb; v.z = fminf(fmaxf(t + 3.f, 0.f), 6.f) * (1.f / 6.f) * g.z;
        t = acc[q].w * s + bb; v.w = fminf(fmaxf(t + 3.f, 0.f), 6.f) * (1.f / 6.f) * g.w;
        op[q] = v;
    }
}

extern "C" void kernel_launch(void* const* d_in, const int* in_sizes, int n_in,
                              void* d_out, int out_size, void* d_ws, size_t ws_size,
                              hipStream_t stream) {
    const float* x       = (const float*)d_in[0];
    const float* bn1_s   = (const float*)d_in[1];
    const float* bn1_b   = (const float*)d_in[2];
    const float* fc1_w   = (const float*)d_in[3];
    const float* fc1_b   = (const float*)d_in[4];
    const float* wq      = (const float*)d_in[5];
    const float* bnq_s   = (const float*)d_in[6];
    const float* bnq_b   = (const float*)d_in[7];
    const float* wk      = (const float*)d_in[8];
    const float* bnk_s   = (const float*)d_in[9];
    const float* bnk_b   = (const float*)d_in[10];
    const float* wv      = (const float*)d_in[11];
    const float* bnv_s   = (const float*)d_in[12];
    const float* bnv_b   = (const float*)d_in[13];
    const float* pos_rq  = (const float*)d_in[14];
    const float* pos_rk  = (const float*)d_in[15];
    const float* pos_cq  = (const float*)d_in[16];
    const float* pos_ck  = (const float*)d_in[17];
    const float* wrow    = (const float*)d_in[18];
    const float* bnrow_s = (const float*)d_in[19];
    const float* bnrow_b = (const float*)d_in[20];
    const float* wcol    = (const float*)d_in[21];
    const float* bncol_s = (const float*)d_in[22];
    const float* bncol_b = (const float*)d_in[23];
    const float* wproj   = (const float*)d_in[24];
    const float* bnproj_s= (const float*)d_in[25];
    const float* bnproj_b= (const float*)d_in[26];
    const float* wdw     = (const float*)d_in[27];
    const float* bndw_s  = (const float*)d_in[28];
    const float* bndw_b  = (const float*)d_in[29];
    const float* wpw     = (const float*)d_in[30];
    const float* bnpw_s  = (const float*)d_in[31];
    const float* bnpw_b  = (const float*)d_in[32];

    char* ws = (char*)d_ws;
    float* qkv_a  = (float*)(ws);                          // 134217728 B [8,256,128,128] f32
    short* t0ph   = (short*)(ws + (size_t)134217728);      // 34611200 B [8,130,130,128] bf16
    short* t0pl   = (short*)(ws + (size_t)168828928);      // 34611200 B
    float* ybuf   = (float*)(ws + (size_t)203440128);      // 67108864 B
    float* qkv_dw = (float*)(ws + (size_t)134217728);      // 134217728 B (reuses t0p+ybuf, both dead by then)
    float* qkv_b  = (float*)(ws + (size_t)270548992);      // 67108864 B
    char* sm = ws + (size_t)337657856;
    float* rowmean = (float*)sm; sm += 1048576;
    float* colmean = (float*)sm; sm += 1048576;
    float* xr_act  = (float*)sm; sm += 524288;
    float* xc_act  = (float*)sm; sm += 524288;
    float* xr_conv = (float*)sm; sm += 524288;
    float* xc_conv = (float*)sm; sm += 524288;
    float* wqkvT   = (float*)sm; sm += 131072;
    float* sqkv    = (float*)sm; sm += 1024;
    float* bqkv    = (float*)sm; sm += 1024;
    float* wpwT    = (float*)sm; sm += 131072;
    float* wprojT  = (float*)sm; sm += 65536;
    float* wrowT   = (float*)sm; sm += 65536;
    float* wcolT   = (float*)sm; sm += 65536;
    short* wch     = (short*)sm; sm += 294912;
    short* wcl     = (short*)sm; sm += 294912;

    float* out = (float*)d_out;

    // zero padded-border buffers (borders stay 0; interiors overwritten by pool)
    hipMemsetAsync(ws + (size_t)134217728, 0, (size_t)69222400, stream);

    prep_kernel<<<576, 256, 0, stream>>>(wq, wk, wv, bnq_s, bnq_b, bnk_s, bnk_b, bnv_s, bnv_b,
                                         wpw, wproj, wrow, wcol, fc1_w,
                                         wqkvT, sqkv, bqkv, wpwT, wprojT, wrowT, wcolT, wch, wcl);
    pool_kernel<<<dim3(256, 8), 256, 0, stream>>>(x, bn1_s, bn1_b, t0ph, t0pl);
    conv3x3_mfma<<<dim3(128, 8), 256, 0, stream>>>(t0ph, t0pl, wch, wcl, fc1_b, ybuf);
    qkv_kernel<<<2048, 256, 0, stream>>>(ybuf, wqkvT, sqkv, bqkv, qkv_a);
    mean_kernel<<<2048, 128, 0, stream>>>(qkv_a, rowmean, colmean);
    dw_kernel<<<131072, 256, 0, stream>>>(qkv_a, wdw, bndw_s, bndw_b, qkv_dw);
    pw_kernel<<<4096, 256, 0, stream>>>(qkv_dw, wpwT, bnpw_s, bnpw_b, qkv_b);
    attn_kernel<<<64, 128, 0, stream>>>(rowmean, pos_rq, pos_rk, xr_act);
    attn_kernel<<<64, 128, 0, stream>>>(colmean, pos_cq, pos_ck, xc_act);
    rc_conv_kernel<<<32, 256, 0, stream>>>(xr_act, xc_act, wrowT, wcolT,
                                           bnrow_s, bnrow_b, bncol_s, bncol_b, xr_conv, xc_conv);
    final_kernel<<<4096, 256, 0, stream>>>(qkv_a, xr_conv, xc_conv, wprojT,
                                           bnproj_s, bnproj_b, qkv_b, out);
}

// Round 3
// 755.236 us; speedup vs baseline: 6.0276x; 1.4965x over previous
//
#include <hip/hip_runtime.h>
#include <math.h>

#define S 16384      // 128*128 spatial
#define HW 128

typedef __attribute__((ext_vector_type(8))) short short8;
typedef __attribute__((ext_vector_type(4))) float f32x4;

__device__ __forceinline__ float mishf(float t) {
    float sp = (t > 20.0f) ? t : log1pf(expf(t));
    return t * tanhf(sp);
}
__device__ __forceinline__ short f2bf(float f) {   // RNE f32 -> bf16 bits
    unsigned u = __float_as_uint(f);
    unsigned r = (u + 0x7FFFu + ((u >> 16) & 1u)) >> 16;
    return (short)r;
}
__device__ __forceinline__ float bf2f(short s) {
    unsigned u = ((unsigned)(unsigned short)s) << 16;
    return __uint_as_float(u);
}
__device__ __forceinline__ unsigned packhl(float v) {  // lo16=hi part, hi16=lo part
    short h = f2bf(v);
    short l = f2bf(v - bf2f(h));
    return (unsigned)(unsigned short)h | ((unsigned)(unsigned short)l << 16);
}
__device__ __forceinline__ void gl_lds16(const void* g, void* l) {
    __builtin_amdgcn_global_load_lds(
        (const __attribute__((address_space(1))) unsigned int*)g,
        (__attribute__((address_space(3))) unsigned int*)l, 16, 0, 0);
}
// swizzled LDS fragment read: logical byte addr a within a [px][256B] row layout
__device__ __forceinline__ short8 lds_frag(const char* base, int a) {
    int p = a ^ (((a >> 8) & 7) << 4);
    return *(const short8*)(base + p);
}
#define MFMA(a, b, c) __builtin_amdgcn_mfma_f32_16x16x32_bf16(a, b, c, 0, 0, 0)

// ---------------- prep: split/transposed weights ----------------
__global__ void prep_kernel(const float* __restrict__ wq, const float* __restrict__ wk, const float* __restrict__ wv,
                            const float* __restrict__ bnq_s, const float* __restrict__ bnq_b,
                            const float* __restrict__ bnk_s, const float* __restrict__ bnk_b,
                            const float* __restrict__ bnv_s, const float* __restrict__ bnv_b,
                            const float* __restrict__ wpw, const float* __restrict__ wproj,
                            const float* __restrict__ wrow, const float* __restrict__ wcol,
                            const float* __restrict__ fc1_w, const float* __restrict__ wdw,
                            short* __restrict__ wqkv_h, short* __restrict__ wqkv_l,
                            float* __restrict__ sqkv, float* __restrict__ bqkv,
                            short* __restrict__ wpw_h, short* __restrict__ wpw_l,
                            short* __restrict__ wproj_h, short* __restrict__ wproj_l,
                            float* __restrict__ wrowT, float* __restrict__ wcolT,
                            short* __restrict__ wch, short* __restrict__ wcl,
                            float* __restrict__ wdwT) {
    int tid = blockIdx.x * 256 + threadIdx.x;
    if (tid < 256 * 128) {            // wqkv [oc 256][ic 128] split
        int oc = tid >> 7, ic = tid & 127;
        float w = (oc < 64) ? wq[oc * 128 + ic]
                : (oc < 128) ? wk[(oc - 64) * 128 + ic]
                : wv[(oc - 128) * 128 + ic];
        short h = f2bf(w);
        wqkv_h[tid] = h; wqkv_l[tid] = f2bf(w - bf2f(h));
    }
    if (tid < 256) {
        sqkv[tid] = (tid < 64) ? bnq_s[tid] : (tid < 128) ? bnk_s[tid - 64] : bnv_s[tid - 128];
        bqkv[tid] = (tid < 64) ? bnq_b[tid] : (tid < 128) ? bnk_b[tid - 64] : bnv_b[tid - 128];
    }
    if (tid < 128 * 256) {            // wpw [oc 128][ic 256] split (source already [oc][ic])
        float w = wpw[tid];
        short h = f2bf(w);
        wpw_h[tid] = h; wpw_l[tid] = f2bf(w - bf2f(h));
    }
    if (tid < 128 * 128) {
        float w = wproj[tid];         // [oc][ic]
        short h = f2bf(w);
        wproj_h[tid] = h; wproj_l[tid] = f2bf(w - bf2f(h));
        int ic = tid >> 7, oc = tid & 127;
        wrowT[tid] = wrow[oc * 128 + ic];
        wcolT[tid] = wcol[oc * 128 + ic];
    }
    if (tid < 9 * 128 * 128) {        // conv3x3 [tap][oc][ic] split
        int tap = tid >> 14;
        int oc = (tid >> 7) & 127;
        int ic = tid & 127;
        float f = fc1_w[(oc * 128 + ic) * 9 + tap];
        short h = f2bf(f);
        wch[tid] = h; wcl[tid] = f2bf(f - bf2f(h));
    }
    if (tid < 9 * 256) {              // depthwise [tap][c]
        int tap = tid / 256, c = tid % 256;
        wdwT[tap * 256 + c] = wdw[c * 9 + tap];
    }
}

// ---------------- pool (avg+max) + BN + Mish -> padded NHWC split bf16 ----------------
// t0p layout: [8][130][130][128] (borders pre-zeroed)
__global__ __launch_bounds__(256) void pool_kernel(const float* __restrict__ x,
                                                   const float* __restrict__ s1, const float* __restrict__ b1,
                                                   short* __restrict__ t0ph, short* __restrict__ t0pl) {
    __shared__ unsigned ot[64][132];
    int bx = blockIdx.x;               // 0..255
    int b = blockIdx.y;
    int h = bx >> 1, wh = bx & 1;
    int t = threadIdx.x;
    int wl = t & 63, c2 = t >> 6;
    int w = wh * 64 + wl;
    for (int cs = 0; cs < 16; ++cs) {
        int c = cs * 4 + c2;
        const float* xp = x + (size_t)(b * 64 + c) * 65536;
        float sum = 0.f, mx = -INFINITY;
        #pragma unroll
        for (int kh = 0; kh < 3; ++kh) {
            int ih = 2 * h + kh - 1;
            if ((unsigned)ih >= 256u) continue;
            #pragma unroll
            for (int kw = 0; kw < 3; ++kw) {
                int iw = 2 * w + kw - 1;
                if ((unsigned)iw >= 256u) continue;
                float v = xp[ih * 256 + iw];
                sum += v; mx = fmaxf(mx, v);
            }
        }
        float ta = mishf((sum * (1.f / 9.f)) * s1[c] + b1[c]);
        float tm = mishf(mx * s1[64 + c] + b1[64 + c]);
        ot[wl][c] = packhl(ta);
        ot[wl][64 + c] = packhl(tm);
    }
    __syncthreads();
    size_t rowbase = ((size_t)(b * 130 + h + 1) * 130 + 1 + wh * 64) * 128;
    short* oph = t0ph + rowbase;
    short* opl = t0pl + rowbase;
    for (int idx = t; idx < 64 * 16; idx += 256) {
        int wloc = idx >> 4, co = idx & 15;
        short8 hv, lv;
        #pragma unroll
        for (int j = 0; j < 8; ++j) {
            unsigned u = ot[wloc][co * 8 + j];
            hv[j] = (short)(u & 0xFFFFu);
            lv[j] = (short)(u >> 16);
        }
        *(short8*)(oph + wloc * 128 + co * 8) = hv;
        *(short8*)(opl + wloc * 128 + co * 8) = lv;
    }
}

// ---------------- conv3x3 via MFMA, LDS-staged rows -> y NHWC split ----------------
__global__ __launch_bounds__(256) void conv3x3_mfma(const short* __restrict__ t0ph,
                                                    const short* __restrict__ t0pl,
                                                    const short* __restrict__ wch, const short* __restrict__ wcl,
                                                    const float* __restrict__ fb,
                                                    short* __restrict__ yh, short* __restrict__ yl) {
    __shared__ char sm[67584];
    char* smh = sm;
    char* sml = sm + 33792;
    int h = blockIdx.x, b = blockIdx.y;
    int tid = threadIdx.x, lane = tid & 63, wv = tid >> 6;
    int wr = wv >> 1, wc2 = wv & 1;
    int l15 = lane & 15, l4 = lane >> 4;
    int spb = wr * 64 + l15;
    int ocb = wc2 * 64 + l15;
    f32x4 acc[4][4];
    #pragma unroll
    for (int m = 0; m < 4; ++m)
        #pragma unroll
        for (int n = 0; n < 4; ++n) acc[m][n] = (f32x4){0.f, 0.f, 0.f, 0.f};
    for (int kh = 0; kh < 3; ++kh) {
        __syncthreads();
        const char* gh = (const char*)(t0ph + ((size_t)(b * 130 + h + kh) * 130) * 128);
        const char* gl = (const char*)(t0pl + ((size_t)(b * 130 + h + kh) * 130) * 128);
        #pragma unroll
        for (int it = 0; it < 9; ++it) {
            int doff = (it * 4 + wv) * 1024;
            if (doff < 33280) {
                int dl = doff + (lane << 4);
                int srcoff = dl ^ (((dl >> 8) & 7) << 4);
                gl_lds16(gh + srcoff, smh + doff);
                gl_lds16(gl + srcoff, sml + doff);
            }
        }
        __syncthreads();
        #pragma unroll
        for (int kw = 0; kw < 3; ++kw) {
            const short* wbh = wch + (size_t)(kh * 3 + kw) * 16384;
            const short* wbl = wcl + (size_t)(kh * 3 + kw) * 16384;
            #pragma unroll
            for (int ks = 0; ks < 4; ++ks) {
                int kb = ks * 64 + l4 * 16;          // byte offset in K-span
                int kws = ks * 32 + l4 * 8;          // short offset for weights
                short8 ah[4], bh[4];
                #pragma unroll
                for (int m = 0; m < 4; ++m)
                    ah[m] = lds_frag(smh, ((spb + m * 16 + kw) << 8) + kb);
                #pragma unroll
                for (int n = 0; n < 4; ++n)
                    bh[n] = *(const short8*)(wbh + (ocb + n * 16) * 128 + kws);
                #pragma unroll
                for (int m = 0; m < 4; ++m)
                    #pragma unroll
                    for (int n = 0; n < 4; ++n)
                        acc[m][n] = MFMA(ah[m], bh[n], acc[m][n]);
                short8 al[4];
                #pragma unroll
                for (int m = 0; m < 4; ++m)
                    al[m] = lds_frag(sml, ((spb + m * 16 + kw) << 8) + kb);
                #pragma unroll
                for (int m = 0; m < 4; ++m)
                    #pragma unroll
                    for (int n = 0; n < 4; ++n)
                        acc[m][n] = MFMA(al[m], bh[n], acc[m][n]);
                short8 bl[4];
                #pragma unroll
                for (int n = 0; n < 4; ++n)
                    bl[n] = *(const short8*)(wbl + (ocb + n * 16) * 128 + kws);
                #pragma unroll
                for (int m = 0; m < 4; ++m)
                    #pragma unroll
                    for (int n = 0; n < 4; ++n)
                        acc[m][n] = MFMA(ah[m], bl[n], acc[m][n]);
            }
        }
    }
    // epilogue: bias, pack hi/lo, NHWC write via LDS
    float fbv[4];
    #pragma unroll
    for (int n = 0; n < 4; ++n) fbv[n] = fb[wc2 * 64 + n * 16 + l15];
    __syncthreads();
    unsigned* tp = (unsigned*)sm;    // [128][132]
    #pragma unroll
    for (int m = 0; m < 4; ++m)
        #pragma unroll
        for (int n = 0; n < 4; ++n)
            #pragma unroll
            for (int r = 0; r < 4; ++r) {
                int px = wr * 64 + m * 16 + l4 * 4 + r;
                int ocl = wc2 * 64 + n * 16 + l15;
                tp[px * 132 + ocl] = packhl(acc[m][n][r] + fbv[n]);
            }
    __syncthreads();
    for (int i = 0; i < 8; ++i) {
        int idx = tid + i * 256;
        int px = idx >> 4, oc8 = idx & 15;
        const unsigned* row = tp + px * 132 + oc8 * 8;
        short8 hv, lv;
        #pragma unroll
        for (int j = 0; j < 8; ++j) {
            unsigned u = row[j];
            hv[j] = (short)(u & 0xFFFFu);
            lv[j] = (short)(u >> 16);
        }
        size_t o = ((size_t)((b * 128 + h) * 128 + px)) * 128 + oc8 * 8;
        *(short8*)(yh + o) = hv;
        *(short8*)(yl + o) = lv;
    }
}

// ---------------- qkv 1x1 MFMA: y[128] -> qkv[256] + BN, fused rowmean ----------------
__global__ __launch_bounds__(512) void qkv_mfma(const short* __restrict__ yh, const short* __restrict__ yl,
                                                const short* __restrict__ wqkv_h, const short* __restrict__ wqkv_l,
                                                const float* __restrict__ sc, const float* __restrict__ bi,
                                                short* __restrict__ qh, short* __restrict__ ql,
                                                float* __restrict__ rowmean) {
    __shared__ char sm[68608];
    char* smh = sm;
    char* sml = sm + 32768;
    int h = blockIdx.x, b = blockIdx.y;
    int tid = threadIdx.x, lane = tid & 63, wv = tid >> 6;
    int wr = wv >> 2, wcq = wv & 3;
    int l15 = lane & 15, l4 = lane >> 4;
    int spb = wr * 64 + l15;
    int ocb = wcq * 64 + l15;
    // stage y row [128px][128ch] hi/lo with swizzled source
    const char* gh = (const char*)(yh + ((size_t)(b * 128 + h) * 128) * 128);
    const char* gl = (const char*)(yl + ((size_t)(b * 128 + h) * 128) * 128);
    #pragma unroll
    for (int it = 0; it < 4; ++it) {
        int doff = (it * 8 + wv) * 1024;
        int dl = doff + (lane << 4);
        int srcoff = dl ^ (((dl >> 8) & 7) << 4);
        gl_lds16(gh + srcoff, smh + doff);
        gl_lds16(gl + srcoff, sml + doff);
    }
    f32x4 acc[4][4];
    #pragma unroll
    for (int m = 0; m < 4; ++m)
        #pragma unroll
        for (int n = 0; n < 4; ++n) acc[m][n] = (f32x4){0.f, 0.f, 0.f, 0.f};
    __syncthreads();
    #pragma unroll
    for (int ks = 0; ks < 4; ++ks) {
        int kb = ks * 64 + l4 * 16;
        int kws = ks * 32 + l4 * 8;
        short8 ah[4], bh[4];
        #pragma unroll
        for (int m = 0; m < 4; ++m) ah[m] = lds_frag(smh, ((spb + m * 16) << 8) + kb);
        #pragma unroll
        for (int n = 0; n < 4; ++n) bh[n] = *(const short8*)(wqkv_h + (ocb + n * 16) * 128 + kws);
        #pragma unroll
        for (int m = 0; m < 4; ++m)
            #pragma unroll
            for (int n = 0; n < 4; ++n) acc[m][n] = MFMA(ah[m], bh[n], acc[m][n]);
        short8 al[4];
        #pragma unroll
        for (int m = 0; m < 4; ++m) al[m] = lds_frag(sml, ((spb + m * 16) << 8) + kb);
        #pragma unroll
        for (int m = 0; m < 4; ++m)
            #pragma unroll
            for (int n = 0; n < 4; ++n) acc[m][n] = MFMA(al[m], bh[n], acc[m][n]);
        short8 bl[4];
        #pragma unroll
        for (int n = 0; n < 4; ++n) bl[n] = *(const short8*)(wqkv_l + (ocb + n * 16) * 128 + kws);
        #pragma unroll
        for (int m = 0; m < 4; ++m)
            #pragma unroll
            for (int n = 0; n < 4; ++n) acc[m][n] = MFMA(ah[m], bl[n], acc[m][n]);
    }
    float s4[4], b4[4];
    #pragma unroll
    for (int n = 0; n < 4; ++n) {
        s4[n] = sc[wcq * 64 + n * 16 + l15];
        b4[n] = bi[wcq * 64 + n * 16 + l15];
    }
    unsigned* tp = (unsigned*)sm;                 // [128][132]
    float* rowsum = (float*)(sm + 67584);         // [256]
    if (tid < 256) rowsum[tid] = 0.f;
    for (int p = 0; p < 2; ++p) {
        __syncthreads();
        if ((wcq >> 1) == p) {
            #pragma unroll
            for (int m = 0; m < 4; ++m)
                #pragma unroll
                for (int n = 0; n < 4; ++n)
                    #pragma unroll
                    for (int r = 0; r < 4; ++r) {
                        int px = wr * 64 + m * 16 + l4 * 4 + r;
                        int ocl = (wcq & 1) * 64 + n * 16 + l15;
                        tp[px * 132 + ocl] = packhl(acc[m][n][r] * s4[n] + b4[n]);
                    }
        }
        __syncthreads();
        float sum8[8];
        #pragma unroll
        for (int j = 0; j < 8; ++j) sum8[j] = 0.f;
        int oc8 = tid & 15;
        for (int i = 0; i < 4; ++i) {
            int idx = tid + i * 512;
            int px = idx >> 4;
            const unsigned* row = tp + px * 132 + oc8 * 8;
            short8 hv, lv;
            #pragma unroll
            for (int j = 0; j < 8; ++j) {
                unsigned u = row[j];
                hv[j] = (short)(u & 0xFFFFu);
                lv[j] = (short)(u >> 16);
                sum8[j] += bf2f(hv[j]) + bf2f(lv[j]);
            }
            size_t o = ((size_t)((b * 128 + h) * 128 + px)) * 256 + p * 128 + oc8 * 8;
            *(short8*)(qh + o) = hv;
            *(short8*)(ql + o) = lv;
        }
        #pragma unroll
        for (int j = 0; j < 8; ++j)
            atomicAdd(&rowsum[p * 128 + oc8 * 8 + j], sum8[j]);
    }
    __syncthreads();
    if (tid < 256)
        rowmean[((size_t)b * 256 + tid) * 128 + h] = rowsum[tid] * (1.f / 128.f);
}

// ---------------- colmean: mean over h of qkv NHWC ----------------
__global__ __launch_bounds__(256) void colmean_kernel(const short* __restrict__ qh, const short* __restrict__ ql,
                                                      float* __restrict__ colmean) {
    __shared__ float pc[2][4][256];
    int blk = blockIdx.x;
    int b = blk >> 5, w0 = (blk & 31) * 4;
    int tid = threadIdx.x;
    int c8g = tid & 31, wj = (tid >> 5) & 3, part = tid >> 7;
    const short* src = part ? ql : qh;
    float a8[8];
    #pragma unroll
    for (int k = 0; k < 8; ++k) a8[k] = 0.f;
    for (int h = 0; h < 128; ++h) {
        short8 v = *(const short8*)(src + ((size_t)((b * 128 + h) * 128 + w0 + wj)) * 256 + c8g * 8);
        #pragma unroll
        for (int k = 0; k < 8; ++k) a8[k] += bf2f(v[k]);
    }
    #pragma unroll
    for (int k = 0; k < 8; ++k) pc[part][wj][c8g * 8 + k] = a8[k];
    __syncthreads();
    int c = tid;
    for (int j = 0; j < 4; ++j)
        colmean[((size_t)b * 256 + c) * 128 + w0 + j] = (pc[0][j][c] + pc[1][j][c]) * (1.f / 128.f);
}

// ---------------- depthwise 3x3 + BN + ReLU (NHWC split in/out) ----------------
__global__ __launch_bounds__(256) void dw_kernel(const short* __restrict__ qh, const short* __restrict__ ql,
                                                 const float* __restrict__ wdwT,
                                                 const float* __restrict__ s, const float* __restrict__ bb,
                                                 short* __restrict__ oh, short* __restrict__ ol) {
    __shared__ float wsh[9 * 256], ssh[256], bsh[256];
    int blk = blockIdx.x;
    int b = blk >> 11, h = (blk >> 4) & 127, w0 = (blk & 15) * 8;
    int tid = threadIdx.x;
    for (int i = tid; i < 9 * 256; i += 256) wsh[i] = wdwT[i];
    if (tid < 256) { ssh[tid] = s[tid]; bsh[tid] = bb[tid]; }
    __syncthreads();
    int c8 = (tid & 31) * 8, w = w0 + (tid >> 5);
    float acc8[8];
    #pragma unroll
    for (int k = 0; k < 8; ++k) acc8[k] = 0.f;
    #pragma unroll
    for (int kh = 0; kh < 3; ++kh) {
        int ih = h + kh - 1;
        if ((unsigned)ih >= 128u) continue;
        #pragma unroll
        for (int kw = 0; kw < 3; ++kw) {
            int iw = w + kw - 1;
            if ((unsigned)iw >= 128u) continue;
            size_t o = ((size_t)((b * 128 + ih) * 128 + iw)) * 256 + c8;
            short8 vh = *(const short8*)(qh + o);
            short8 vl = *(const short8*)(ql + o);
            const float* wp = &wsh[(kh * 3 + kw) * 256 + c8];
            #pragma unroll
            for (int k = 0; k < 8; ++k)
                acc8[k] += wp[k] * (bf2f(vh[k]) + bf2f(vl[k]));
        }
    }
    short8 hv, lv;
    #pragma unroll
    for (int k = 0; k < 8; ++k) {
        float v = fmaxf(acc8[k] * ssh[c8 + k] + bsh[c8 + k], 0.f);
        unsigned u = packhl(v);
        hv[k] = (short)(u & 0xFFFFu);
        lv[k] = (short)(u >> 16);
    }
    size_t o = ((size_t)((b * 128 + h) * 128 + w)) * 256 + c8;
    *(short8*)(oh + o) = hv;
    *(short8*)(ol + o) = lv;
}

// ---------------- pointwise 256->128 MFMA + BN -> qkv_b f32 NHWC ----------------
__global__ __launch_bounds__(256) void pw_mfma(const short* __restrict__ dh, const short* __restrict__ dl,
                                               const short* __restrict__ wpw_h, const short* __restrict__ wpw_l,
                                               const float* __restrict__ sc, const float* __restrict__ bi,
                                               float* __restrict__ qb) {
    __shared__ char sm[67584];
    char* smh = sm;
    char* sml = sm + 32768;
    int h = blockIdx.x, b = blockIdx.y;
    int tid = threadIdx.x, lane = tid & 63, wv = tid >> 6;
    int wr = wv >> 1, wc2 = wv & 1;
    int l15 = lane & 15, l4 = lane >> 4;
    int spb = wr * 64 + l15;
    int ocb = wc2 * 64 + l15;
    const char* rh = (const char*)(dh + ((size_t)(b * 128 + h) * 128) * 256);
    const char* rl = (const char*)(dl + ((size_t)(b * 128 + h) * 128) * 256);
    f32x4 acc[4][4];
    #pragma unroll
    for (int m = 0; m < 4; ++m)
        #pragma unroll
        for (int n = 0; n < 4; ++n) acc[m][n] = (f32x4){0.f, 0.f, 0.f, 0.f};
    for (int kc = 0; kc < 2; ++kc) {
        __syncthreads();
        #pragma unroll
        for (int it = 0; it < 8; ++it) {
            int doff = (it * 4 + wv) * 1024;
            int dl_ = doff + (lane << 4);
            int px_ = dl_ >> 8;
            int kbyt = (dl_ ^ ((px_ & 7) << 4)) & 255;
            int srcoff = px_ * 512 + kc * 256 + kbyt;
            gl_lds16(rh + srcoff, smh + doff);
            gl_lds16(rl + srcoff, sml + doff);
        }
        __syncthreads();
        #pragma unroll
        for (int ks = 0; ks < 4; ++ks) {
            int kb = ks * 64 + l4 * 16;
            int kws = kc * 128 + ks * 32 + l4 * 8;
            short8 ah[4], bh[4];
            #pragma unroll
            for (int m = 0; m < 4; ++m) ah[m] = lds_frag(smh, ((spb + m * 16) << 8) + kb);
            #pragma unroll
            for (int n = 0; n < 4; ++n) bh[n] = *(const short8*)(wpw_h + (ocb + n * 16) * 256 + kws);
            #pragma unroll
            for (int m = 0; m < 4; ++m)
                #pragma unroll
                for (int n = 0; n < 4; ++n) acc[m][n] = MFMA(ah[m], bh[n], acc[m][n]);
            short8 al[4];
            #pragma unroll
            for (int m = 0; m < 4; ++m) al[m] = lds_frag(sml, ((spb + m * 16) << 8) + kb);
            #pragma unroll
            for (int m = 0; m < 4; ++m)
                #pragma unroll
                for (int n = 0; n < 4; ++n) acc[m][n] = MFMA(al[m], bh[n], acc[m][n]);
            short8 bl[4];
            #pragma unroll
            for (int n = 0; n < 4; ++n) bl[n] = *(const short8*)(wpw_l + (ocb + n * 16) * 256 + kws);
            #pragma unroll
            for (int m = 0; m < 4; ++m)
                #pragma unroll
                for (int n = 0; n < 4; ++n) acc[m][n] = MFMA(ah[m], bl[n], acc[m][n]);
        }
    }
    float s4[4], b4[4];
    #pragma unroll
    for (int n = 0; n < 4; ++n) {
        s4[n] = sc[wc2 * 64 + n * 16 + l15];
        b4[n] = bi[wc2 * 64 + n * 16 + l15];
    }
    __syncthreads();
    float* tpf = (float*)sm;   // [128][132]
    #pragma unroll
    for (int m = 0; m < 4; ++m)
        #pragma unroll
        for (int n = 0; n < 4; ++n)
            #pragma unroll
            for (int r = 0; r < 4; ++r) {
                int px = wr * 64 + m * 16 + l4 * 4 + r;
                int ocl = wc2 * 64 + n * 16 + l15;
                tpf[px * 132 + ocl] = acc[m][n][r] * s4[n] + b4[n];
            }
    __syncthreads();
    for (int i = 0; i < 16; ++i) {
        int idx = tid + i * 256;
        int px = idx >> 5, oc4 = idx & 31;
        const float* row = tpf + px * 132 + oc4 * 4;
        float4 v = make_float4(row[0], row[1], row[2], row[3]);
        *(float4*)(qb + ((size_t)((b * 128 + h) * 128 + px)) * 128 + oc4 * 4) = v;
    }
}

// ---------------- axial attention (row or col) -> relu'd output ----------------
__global__ __launch_bounds__(128) void attn_kernel(const float* __restrict__ meanbuf,  // [8][256][128]
                                                   const float* __restrict__ posq,
                                                   const float* __restrict__ posk,
                                                   float* __restrict__ xact) {        // [8][128][128]
    __shared__ float qr[8][128], kr[8][128], vr[16][128];
    int b = blockIdx.x >> 3, head = blockIdx.x & 7;
    int i = threadIdx.x;
    float src = (i + 0.5f) * 0.125f - 0.5f;
    src = fmaxf(src, 0.f);
    int i0 = (int)src;
    if (i0 > 15) i0 = 15;
    float f = src - (float)i0;
    int i1 = (i0 + 1 > 15) ? 15 : i0 + 1;
    const float* mb = meanbuf + (size_t)b * 256 * 128;
    for (int kd = 0; kd < 8; ++kd) {
        int cq = head * 8 + kd;
        qr[kd][i] = mb[cq * 128 + i] + posq[cq * 16 + i0] * (1.f - f) + posq[cq * 16 + i1] * f;
        kr[kd][i] = mb[(64 + cq) * 128 + i] + posk[cq * 16 + i0] * (1.f - f) + posk[cq * 16 + i1] * f;
    }
    for (int d = 0; d < 16; ++d)
        vr[d][i] = mb[(128 + head * 16 + d) * 128 + i];
    __syncthreads();
    float qreg[8];
    #pragma unroll
    for (int kd = 0; kd < 8; ++kd) qreg[kd] = qr[kd][i];
    const float scale = 0.35355339059327373f;
    float m = -INFINITY;
    for (int j = 0; j < 128; ++j) {
        float sj = 0.f;
        #pragma unroll
        for (int kd = 0; kd < 8; ++kd) sj += qreg[kd] * kr[kd][j];
        m = fmaxf(m, sj * scale);
    }
    float denom = 0.f;
    float acc[16];
    #pragma unroll
    for (int d = 0; d < 16; ++d) acc[d] = 0.f;
    for (int j = 0; j < 128; ++j) {
        float sj = 0.f;
        #pragma unroll
        for (int kd = 0; kd < 8; ++kd) sj += qreg[kd] * kr[kd][j];
        float pj = expf(sj * scale - m);
        denom += pj;
        #pragma unroll
        for (int d = 0; d < 16; ++d) acc[d] += pj * vr[d][j];
    }
    float inv = 1.f / denom;
    float* xp = xact + ((size_t)b * 128 + head * 16) * 128;
    for (int d = 0; d < 16; ++d)
        xp[d * 128 + i] = fmaxf(acc[d] * inv, 0.f);
}

// ---------------- 1x1 conv on xr/xc + BN -> TRANSPOSED [b][i][ic] outputs ----------------
__global__ __launch_bounds__(256) void rc_conv_kernel(const float* __restrict__ xr_act, const float* __restrict__ xc_act,
                                                      const float* __restrict__ wrowT, const float* __restrict__ wcolT,
                                                      const float* __restrict__ rs, const float* __restrict__ rb,
                                                      const float* __restrict__ cs, const float* __restrict__ cb,
                                                      float* __restrict__ xrT, float* __restrict__ xcT) {
    __shared__ float4 lds[128][16];
    int blk = blockIdx.x;             // 0..31
    int iscol = blk >> 4;
    int rem = blk & 15;
    int b = rem >> 1;
    int i0 = (rem & 1) * 64;
    const float* src = iscol ? xc_act : xr_act;
    const float* wT  = iscol ? wcolT : wrowT;
    const float* ss  = iscol ? cs : rs;
    const float* sb  = iscol ? cb : rb;
    float* dst       = iscol ? xcT : xrT;
    int tid = threadIdx.x;
    const float4* src4 = (const float4*)(src + (size_t)b * 16384 + i0);
    for (int idx = tid; idx < 128 * 16; idx += 256) {
        int ic = idx >> 4, q = idx & 15;
        lds[ic][q] = src4[ic * 32 + q];
    }
    __syncthreads();
    int oc = tid & 127, sub = tid >> 7;
    float4 acc[8];
    #pragma unroll
    for (int q = 0; q < 8; ++q) acc[q] = make_float4(0.f, 0.f, 0.f, 0.f);
    for (int ic = 0; ic < 128; ++ic) {
        float w = wT[ic * 128 + oc];
        #pragma unroll
        for (int q = 0; q < 8; ++q) {
            float4 v = lds[ic][sub * 8 + q];
            acc[q].x += w * v.x; acc[q].y += w * v.y;
            acc[q].z += w * v.z; acc[q].w += w * v.w;
        }
    }
    float s = ss[oc], bb = sb[oc];
    int ibase = i0 + sub * 32;
    #pragma unroll
    for (int q = 0; q < 8; ++q) {
        float vv[4] = {acc[q].x, acc[q].y, acc[q].z, acc[q].w};
        #pragma unroll
        for (int r = 0; r < 4; ++r) {
            int i = ibase + q * 4 + r;
            dst[((size_t)b * 128 + i) * 128 + oc] = vv[r] * s + bb;
        }
    }
}

// ---------------- final: xx=v+xr+xc, relu, proj MFMA + BN, hsig*qkv_b -> out NCHW ----------------
__global__ __launch_bounds__(256) void final_mfma(const short* __restrict__ qh, const short* __restrict__ ql,
                                                  const float* __restrict__ xrT, const float* __restrict__ xcT,
                                                  const short* __restrict__ wproj_h, const short* __restrict__ wproj_l,
                                                  const float* __restrict__ ps, const float* __restrict__ pb,
                                                  const float* __restrict__ qb, float* __restrict__ out) {
    __shared__ char sm[69632];
    short* ahi = (short*)sm;              // [128][136]
    short* alo = (short*)(sm + 34816);    // [128][136]
    int h = blockIdx.x, b = blockIdx.y;
    int tid = threadIdx.x, lane = tid & 63, wv = tid >> 6;
    int wr = wv >> 1, wc2 = wv & 1;
    int l15 = lane & 15, l4 = lane >> 4;
    int spb = wr * 64 + l15;
    int ocb = wc2 * 64 + l15;
    // build A = split(relu(v + xr + xc))
    for (int i = 0; i < 8; ++i) {
        int idx = tid + i * 256;
        int px = idx >> 4, g = idx & 15;
        size_t vo = ((size_t)((b * 128 + h) * 128 + px)) * 256 + 128 + g * 8;
        short8 vh = *(const short8*)(qh + vo);
        short8 vl = *(const short8*)(ql + vo);
        const float* xr = xrT + ((size_t)(b * 128 + h)) * 128 + g * 8;
        const float* xc = xcT + ((size_t)(b * 128 + px)) * 128 + g * 8;
        short8 hv, lv;
        #pragma unroll
        for (int k = 0; k < 8; ++k) {
            float v = bf2f(vh[k]) + bf2f(vl[k]) + xr[k] + xc[k];
            v = fmaxf(v, 0.f);
            unsigned u = packhl(v);
            hv[k] = (short)(u & 0xFFFFu);
            lv[k] = (short)(u >> 16);
        }
        *(short8*)(ahi + px * 136 + g * 8) = hv;
        *(short8*)(alo + px * 136 + g * 8) = lv;
    }
    __syncthreads();
    f32x4 acc[4][4];
    #pragma unroll
    for (int m = 0; m < 4; ++m)
        #pragma unroll
        for (int n = 0; n < 4; ++n) acc[m][n] = (f32x4){0.f, 0.f, 0.f, 0.f};
    #pragma unroll
    for (int ks = 0; ks < 4; ++ks) {
        int ko = ks * 32 + l4 * 8;
        short8 ah[4], bh[4];
        #pragma unroll
        for (int m = 0; m < 4; ++m) ah[m] = *(const short8*)(ahi + (spb + m * 16) * 136 + ko);
        #pragma unroll
        for (int n = 0; n < 4; ++n) bh[n] = *(const short8*)(wproj_h + (ocb + n * 16) * 128 + ko);
        #pragma unroll
        for (int m = 0; m < 4; ++m)
            #pragma unroll
            for (int n = 0; n < 4; ++n) acc[m][n] = MFMA(ah[m], bh[n], acc[m][n]);
        short8 al[4];
        #pragma unroll
        for (int m = 0; m < 4; ++m) al[m] = *(const short8*)(alo + (spb + m * 16) * 136 + ko);
        #pragma unroll
        for (int m = 0; m < 4; ++m)
            #pragma unroll
            for (int n = 0; n < 4; ++n) acc[m][n] = MFMA(al[m], bh[n], acc[m][n]);
        short8 bl[4];
        #pragma unroll
        for (int n = 0; n < 4; ++n) bl[n] = *(const short8*)(wproj_l + (ocb + n * 16) * 128 + ko);
        #pragma unroll
        for (int m = 0; m < 4; ++m)
            #pragma unroll
            for (int n = 0; n < 4; ++n) acc[m][n] = MFMA(ah[m], bl[n], acc[m][n]);
    }
    float s4[4], b4[4];
    #pragma unroll
    for (int n = 0; n < 4; ++n) {
        s4[n] = ps[wc2 * 64 + n * 16 + l15];
        b4[n] = pb[wc2 * 64 + n * 16 + l15];
    }
    float* tr = (float*)sm;    // [64][129]
    #pragma unroll 1
    for (int p = 0; p < 2; ++p) {
        __syncthreads();
        if (wc2 == p) {
            #pragma unroll
            for (int n = 0; n < 4; ++n)
                #pragma unroll
                for (int m = 0; m < 4; ++m)
                    #pragma unroll
                    for (int r = 0; r < 4; ++r) {
                        int px = wr * 64 + m * 16 + l4 * 4 + r;
                        int oc = p * 64 + n * 16 + l15;
                        float val = acc[m][n][r] * s4[n] + b4[n];
                        float hs = fminf(fmaxf(val + 3.f, 0.f), 6.f) * (1.f / 6.f);
                        float g = qb[((size_t)((b * 128 + h) * 128 + px)) * 128 + oc];
                        tr[(n * 16 + l15) * 129 + px] = hs * g;
                    }
        }
        __syncthreads();
        int ocl = tid >> 2, q = tid & 3;
        int oc = p * 64 + ocl;
        float* yp = out + (size_t)(b * 128 + oc) * S + h * 128 + q * 32;
        #pragma unroll
        for (int j = 0; j < 32; j += 4) {
            float4 v;
            v.x = tr[ocl * 129 + q * 32 + j];
            v.y = tr[ocl * 129 + q * 32 + j + 1];
            v.z = tr[ocl * 129 + q * 32 + j + 2];
            v.w = tr[ocl * 129 + q * 32 + j + 3];
            *(float4*)(yp + j) = v;
        }
    }
}

extern "C" void kernel_launch(void* const* d_in, const int* in_sizes, int n_in,
                              void* d_out, int out_size, void* d_ws, size_t ws_size,
                              hipStream_t stream) {
    const float* x       = (const float*)d_in[0];
    const float* bn1_s   = (const float*)d_in[1];
    const float* bn1_b   = (const float*)d_in[2];
    const float* fc1_w   = (const float*)d_in[3];
    const float* fc1_b   = (const float*)d_in[4];
    const float* wq      = (const float*)d_in[5];
    const float* bnq_s   = (const float*)d_in[6];
    const float* bnq_b   = (const float*)d_in[7];
    const float* wk      = (const float*)d_in[8];
    const float* bnk_s   = (const float*)d_in[9];
    const float* bnk_b   = (const float*)d_in[10];
    const float* wv      = (const float*)d_in[11];
    const float* bnv_s   = (const float*)d_in[12];
    const float* bnv_b   = (const float*)d_in[13];
    const float* pos_rq  = (const float*)d_in[14];
    const float* pos_rk  = (const float*)d_in[15];
    const float* pos_cq  = (const float*)d_in[16];
    const float* pos_ck  = (const float*)d_in[17];
    const float* wrow    = (const float*)d_in[18];
    const float* bnrow_s = (const float*)d_in[19];
    const float* bnrow_b = (const float*)d_in[20];
    const float* wcol    = (const float*)d_in[21];
    const float* bncol_s = (const float*)d_in[22];
    const float* bncol_b = (const float*)d_in[23];
    const float* wproj   = (const float*)d_in[24];
    const float* bnproj_s= (const float*)d_in[25];
    const float* bnproj_b= (const float*)d_in[26];
    const float* wdw     = (const float*)d_in[27];
    const float* bndw_s  = (const float*)d_in[28];
    const float* bndw_b  = (const float*)d_in[29];
    const float* wpw     = (const float*)d_in[30];
    const float* bnpw_s  = (const float*)d_in[31];
    const float* bnpw_b  = (const float*)d_in[32];

    char* ws = (char*)d_ws;
    // big regions
    short* t0ph  = (short*)(ws);                        // 34,611,200  [8][130][130][128]
    short* t0pl  = (short*)(ws + (size_t)34611200);     // 34,611,200
    short* yh    = (short*)(ws + (size_t)69222400);     // 33,554,432  [8][128][128][128]
    short* yl    = (short*)(ws + (size_t)102776832);    // 33,554,432
    short* qkvh  = (short*)(ws + (size_t)136331264);    // 67,108,864  [8][128][128][256]
    short* qkvl  = (short*)(ws + (size_t)203440128);    // 67,108,864
    float* qkvb  = (float*)(ws + (size_t)270548992);    // 67,108,864  [8][128][128][128] f32
    short* dwoh  = (short*)(ws);                        // reuse t0p region (67,108,864)
    short* dwol  = (short*)(ws + (size_t)69222400);     // reuse y region (67,108,864)
    char* sp = ws + (size_t)337657856;
    float* rowmean = (float*)sp; sp += 1048576;
    float* colmean = (float*)sp; sp += 1048576;
    float* xr_act  = (float*)sp; sp += 524288;
    float* xc_act  = (float*)sp; sp += 524288;
    float* xrT     = (float*)sp; sp += 524288;
    float* xcT     = (float*)sp; sp += 524288;
    short* wch     = (short*)sp; sp += 294912;
    short* wcl     = (short*)sp; sp += 294912;
    short* wqkv_h  = (short*)sp; sp += 65536;
    short* wqkv_l  = (short*)sp; sp += 65536;
    short* wpw_h   = (short*)sp; sp += 65536;
    short* wpw_l   = (short*)sp; sp += 65536;
    short* wproj_h = (short*)sp; sp += 32768;
    short* wproj_l = (short*)sp; sp += 32768;
    float* wrowT   = (float*)sp; sp += 65536;
    float* wcolT   = (float*)sp; sp += 65536;
    float* sqkv    = (float*)sp; sp += 1024;
    float* bqkv    = (float*)sp; sp += 1024;
    float* wdwT    = (float*)sp; sp += 9216;

    float* out = (float*)d_out;

    // zero t0p borders
    hipMemsetAsync(ws, 0, (size_t)69222400, stream);

    prep_kernel<<<576, 256, 0, stream>>>(wq, wk, wv, bnq_s, bnq_b, bnk_s, bnk_b, bnv_s, bnv_b,
                                         wpw, wproj, wrow, wcol, fc1_w, wdw,
                                         wqkv_h, wqkv_l, sqkv, bqkv, wpw_h, wpw_l,
                                         wproj_h, wproj_l, wrowT, wcolT, wch, wcl, wdwT);
    pool_kernel<<<dim3(256, 8), 256, 0, stream>>>(x, bn1_s, bn1_b, t0ph, t0pl);
    conv3x3_mfma<<<dim3(128, 8), 256, 0, stream>>>(t0ph, t0pl, wch, wcl, fc1_b, yh, yl);
    qkv_mfma<<<dim3(128, 8), 512, 0, stream>>>(yh, yl, wqkv_h, wqkv_l, sqkv, bqkv,
                                               qkvh, qkvl, rowmean);
    colmean_kernel<<<256, 256, 0, stream>>>(qkvh, qkvl, colmean);
    dw_kernel<<<16384, 256, 0, stream>>>(qkvh, qkvl, wdwT, bndw_s, bndw_b, dwoh, dwol);
    pw_mfma<<<dim3(128, 8), 256, 0, stream>>>(dwoh, dwol, wpw_h, wpw_l, bnpw_s, bnpw_b, qkvb);
    attn_kernel<<<64, 128, 0, stream>>>(rowmean, pos_rq, pos_rk, xr_act);
    attn_kernel<<<64, 128, 0, stream>>>(colmean, pos_cq, pos_ck, xc_act);
    rc_conv_kernel<<<32, 256, 0, stream>>>(xr_act, xc_act, wrowT, wcolT,
                                           bnrow_s, bnrow_b, bncol_s, bncol_b, xrT, xcT);
    final_mfma<<<dim3(128, 8), 256, 0, stream>>>(qkvh, qkvl, xrT, xcT, wproj_h, wproj_l,
                                                 bnproj_s, bnproj_b, qkvb, out);
}